// Round 1
// baseline (108.480 us; speedup 1.0000x reference)
//
#include <hip/hip_runtime.h>
#include <math.h>

#define NROWS 2048
#define KDIM  20000
#define PDIM  32
#define NWIN  79              // ceil(KDIM / 256)
#define CCH   3               // k-chunks per row-group
#define MAINB (NROWS / 8 * CCH)   // 768 main blocks
#define PRIORB 64
#define STATS_N (NROWS * 4)

__device__ __forceinline__ float wredf(float v) {
#pragma unroll
  for (int o = 32; o > 0; o >>= 1) v += __shfl_down(v, o, 64);
  return v;
}
__device__ __forceinline__ double wredd(double v) {
#pragma unroll
  for (int o = 32; o > 0; o >>= 1) v += __shfl_down(v, o, 64);
  return v;
}

__global__ void init_ws_k(float* stats, double* acc) {
  int i = blockIdx.x * blockDim.x + threadIdx.x;
  if (i < STATS_N) stats[i] = 0.0f;
  if (i == 0) acc[0] = 0.0;
}

// Main kernel: blocks [0, MAINB) stream Y/beta and accumulate per-row stats;
// blocks [MAINB, MAINB+PRIORB) compute the Gaussian prior term.
__global__ __launch_bounds__(256, 3) void mainprior_k(
    const float* __restrict__ X, const int* __restrict__ Y,
    const float* __restrict__ mu, const float* __restrict__ beta,
    const float* __restrict__ m0p, const float* __restrict__ s0p,
    float* __restrict__ stats, double* __restrict__ acc)
{
  __shared__ float lgt[128];
  __shared__ float red[4];
  const int tid = threadIdx.x;

  if (blockIdx.x >= MAINB) {
    // ---------------- prior blocks ----------------
    const int b = blockIdx.x - MAINB;
    const float m0 = m0p[0], s0 = s0p[0];
    const float inv2s2 = 0.5f / (s0 * s0);
    const float cnst = -0.5f * logf(6.283185307179586f * s0 * s0);
    const int total = KDIM + PDIM * KDIM;   // mu then beta, conceptually concat
    float fs = 0.0f;
    for (int i = b * 256 + tid; i < total; i += PRIORB * 256) {
      float v = (i < KDIM) ? mu[i] : beta[i - KDIM];
      float d = v - m0;
      fs += cnst - d * d * inv2s2;
    }
    fs = wredf(fs);
    if ((tid & 63) == 0) red[tid >> 6] = fs;
    __syncthreads();
    if (tid == 0) {
      double t = (double)red[0] + (double)red[1] + (double)red[2] + (double)red[3];
      atomicAdd(acc, t);
    }
    return;
  }

  // ---------------- main blocks ----------------
  const int g = blockIdx.x / CCH;       // row group (8 rows)
  const int c = blockIdx.x - g * CCH;   // k-chunk id
  const int wave = tid >> 6;
  const int lane = tid & 63;
  const int rowa = g * 8 + wave * 2;    // each wave owns 2 rows
  const int rowb = rowa + 1;

  if (tid < 128) lgt[tid] = lgammaf((float)tid + 1.0f);
  __syncthreads();

  // X rows in registers: zero LDS traffic on the inner dot product
  float xa[PDIM], xb[PDIM];
#pragma unroll
  for (int p = 0; p < PDIM; p += 4) {
    float4 va = *(const float4*)(X + rowa * PDIM + p);
    float4 vb = *(const float4*)(X + rowb * PDIM + p);
    xa[p] = va.x; xa[p + 1] = va.y; xa[p + 2] = va.z; xa[p + 3] = va.w;
    xb[p] = vb.x; xb[p + 1] = vb.y; xb[p + 2] = vb.z; xb[p + 3] = vb.w;
  }

  float Sa = 0.f, SYa = 0.f, SYLa = 0.f, SLGa = 0.f;
  float Sb = 0.f, SYb = 0.f, SYLb = 0.f, SLGb = 0.f;

  for (int w = c; w < NWIN; w += CCH) {
    const int k0 = w * 256 + lane * 4;   // wave covers 256 consecutive k
    if (k0 < KDIM) {
      float4 m4 = *(const float4*)(mu + k0);
      float la0 = m4.x, la1 = m4.y, la2 = m4.z, la3 = m4.w;
      float lb0 = m4.x, lb1 = m4.y, lb2 = m4.z, lb3 = m4.w;
      const float* bp = beta + k0;
#pragma unroll
      for (int p = 0; p < PDIM; ++p) {
        float4 b4 = *(const float4*)(bp + p * KDIM);
        la0 += xa[p] * b4.x; la1 += xa[p] * b4.y;
        la2 += xa[p] * b4.z; la3 += xa[p] * b4.w;
        lb0 += xb[p] * b4.x; lb1 += xb[p] * b4.y;
        lb2 += xb[p] * b4.z; lb3 += xb[p] * b4.w;
      }
      int4 ya = *(const int4*)(Y + rowa * KDIM + k0);
      int4 yb = *(const int4*)(Y + rowb * KDIM + k0);
      // logits bounded ~|36| => exp never overflows f32; no max-shift needed
      Sa += __expf(la0) + __expf(la1) + __expf(la2) + __expf(la3);
      Sb += __expf(lb0) + __expf(lb1) + __expf(lb2) + __expf(lb3);
      float fa0 = (float)ya.x, fa1 = (float)ya.y, fa2 = (float)ya.z, fa3 = (float)ya.w;
      float fb0 = (float)yb.x, fb1 = (float)yb.y, fb2 = (float)yb.z, fb3 = (float)yb.w;
      SYa += fa0 + fa1 + fa2 + fa3;
      SYb += fb0 + fb1 + fb2 + fb3;
      SYLa += fa0 * la0 + fa1 * la1 + fa2 * la2 + fa3 * la3;
      SYLb += fb0 * lb0 + fb1 * lb1 + fb2 * lb2 + fb3 * lb3;
      SLGa += lgt[ya.x] + lgt[ya.y] + lgt[ya.z] + lgt[ya.w];
      SLGb += lgt[yb.x] + lgt[yb.y] + lgt[yb.z] + lgt[yb.w];
    }
    __syncthreads();   // keep 4 waves lockstep on the same 32KB beta window (L1 reuse)
  }

  Sa = wredf(Sa); SYa = wredf(SYa); SYLa = wredf(SYLa); SLGa = wredf(SLGa);
  Sb = wredf(Sb); SYb = wredf(SYb); SYLb = wredf(SYLb); SLGb = wredf(SLGb);
  if (lane == 0) {
    atomicAdd(&stats[rowa * 4 + 0], Sa);
    atomicAdd(&stats[rowa * 4 + 1], SYa);
    atomicAdd(&stats[rowa * 4 + 2], SYLa);
    atomicAdd(&stats[rowa * 4 + 3], SLGa);
    atomicAdd(&stats[rowb * 4 + 0], Sb);
    atomicAdd(&stats[rowb * 4 + 1], SYb);
    atomicAdd(&stats[rowb * 4 + 2], SYLb);
    atomicAdd(&stats[rowb * 4 + 3], SLGb);
  }
}

// Per-row nonlinearity + final scalar. Single block.
__global__ void combine_k(const float* __restrict__ stats,
                          const double* __restrict__ acc,
                          float* __restrict__ out)
{
  double part = 0.0;
  for (int r = threadIdx.x; r < NROWS; r += 256) {
    float S   = stats[r * 4 + 0];
    float n   = stats[r * 4 + 1];   // exact: integer sums < 2^24
    float SYL = stats[r * 4 + 2];
    float SLG = stats[r * 4 + 3];
    part += (double)lgammaf(n + 1.0f) - (double)SLG + (double)SYL
          - (double)n * (double)logf(S);
  }
  part = wredd(part);
  __shared__ double pd[4];
  if ((threadIdx.x & 63) == 0) pd[threadIdx.x >> 6] = part;
  __syncthreads();
  if (threadIdx.x == 0) {
    out[0] = (float)(pd[0] + pd[1] + pd[2] + pd[3] + acc[0]);
  }
}

extern "C" void kernel_launch(void* const* d_in, const int* in_sizes, int n_in,
                              void* d_out, int out_size, void* d_ws, size_t ws_size,
                              hipStream_t stream) {
  const float* X    = (const float*)d_in[0];
  const int*   Y    = (const int*)d_in[1];
  const float* mu   = (const float*)d_in[2];
  const float* beta = (const float*)d_in[3];
  const float* m0   = (const float*)d_in[4];
  const float* s0   = (const float*)d_in[5];
  float* out = (float*)d_out;

  float*  stats = (float*)d_ws;
  double* acc   = (double*)((char*)d_ws + STATS_N * sizeof(float));

  init_ws_k<<<dim3((STATS_N + 255) / 256), dim3(256), 0, stream>>>(stats, acc);
  mainprior_k<<<dim3(MAINB + PRIORB), dim3(256), 0, stream>>>(
      X, Y, mu, beta, m0, s0, stats, acc);
  combine_k<<<dim3(1), dim3(256), 0, stream>>>(stats, acc, out);
}